// Round 2
// baseline (174.670 us; speedup 1.0000x reference)
//
#include <hip/hip_runtime.h>

#define Bn 8
#define Ln 256
#define Dn 128
#define Hn 6
#define En 32
#define WXROW (Hn + 2*Dn + En)   // 294
#define ROWS 4                   // i-rows per k_gcn block

// -------- Kernel 1: gcn + out + n1/n2 --------
// grid = B * (L/ROWS) = 512 blocks, 256 threads
__global__ __launch_bounds__(256) void k_gcn(
    const float* __restrict__ x, const float* __restrict__ wadj,
    const float* __restrict__ W_w, const float* __restrict__ W_b,
    const float* __restrict__ Wx_w,
    const float* __restrict__ Wxx_w, const float* __restrict__ Wxx_b,
    float* __restrict__ out, float* __restrict__ n1_ws, float* __restrict__ n2_ws)
{
    __shared__ float adj[ROWS][Ln];        // 4 KB
    __shared__ float part[8][ROWS][Dn];    // 16 KB
    __shared__ float t_s[ROWS][Dn];        // 2 KB
    __shared__ float g_s[ROWS][Dn];        // 2 KB

    const int t  = threadIdx.x;
    const int b  = blockIdx.x >> 6;            // 64 blocks per batch
    const int i0 = (blockIdx.x & 63) * ROWS;

    // 1) adj[r][j] = mean_h wadj[b,h,i0+r,j]  — float4 per thread: (r = t>>6, j4 = t&63)
    {
        const int r  = t >> 6;
        const int j4 = t & 63;
        const float4* w4 = (const float4*)wadj;
        float4 sum = {0.f, 0.f, 0.f, 0.f};
        #pragma unroll
        for (int h = 0; h < Hn; ++h) {
            const float4 v = w4[(((size_t)b * Hn + h) * Ln + (i0 + r)) * (Ln / 4) + j4];
            sum.x += v.x; sum.y += v.y; sum.z += v.z; sum.w += v.w;
        }
        const float inv_h = 1.0f / 6.0f;
        sum.x *= inv_h; sum.y *= inv_h; sum.z *= inv_h; sum.w *= inv_h;
        ((float4*)&adj[0][0])[r * (Ln / 4) + j4] = sum;
    }
    __syncthreads();

    // 2) t[r][d] = sum_j adj[r][j] * x[b,j,d]
    //    256 thr = (q = t>>5 in 0..7: j-slice) x (d4 = t&31: float4 column)
    {
        const int q  = t >> 5;
        const int d4 = t & 31;
        float4 acc[ROWS];
        #pragma unroll
        for (int r = 0; r < ROWS; ++r) acc[r] = {0.f, 0.f, 0.f, 0.f};

        const float4* xp4 = (const float4*)(x + (size_t)b * Ln * Dn) + d4;
        const float4* adj4 = (const float4*)&adj[0][0];
        const int j0 = q * 32;

        #pragma unroll 2
        for (int jj4 = 0; jj4 < 8; ++jj4) {
            const int j = j0 + jj4 * 4;
            const float4 xv0 = xp4[(size_t)(j + 0) * 32];
            const float4 xv1 = xp4[(size_t)(j + 1) * 32];
            const float4 xv2 = xp4[(size_t)(j + 2) * 32];
            const float4 xv3 = xp4[(size_t)(j + 3) * 32];
            #pragma unroll
            for (int r = 0; r < ROWS; ++r) {
                const float4 a = adj4[r * (Ln / 4) + (j >> 2)];
                float4 v = acc[r];
                v.x = fmaf(a.x, xv0.x, v.x); v.y = fmaf(a.x, xv0.y, v.y);
                v.z = fmaf(a.x, xv0.z, v.z); v.w = fmaf(a.x, xv0.w, v.w);
                v.x = fmaf(a.y, xv1.x, v.x); v.y = fmaf(a.y, xv1.y, v.y);
                v.z = fmaf(a.y, xv1.z, v.z); v.w = fmaf(a.y, xv1.w, v.w);
                v.x = fmaf(a.z, xv2.x, v.x); v.y = fmaf(a.z, xv2.y, v.y);
                v.z = fmaf(a.z, xv2.z, v.z); v.w = fmaf(a.z, xv2.w, v.w);
                v.x = fmaf(a.w, xv3.x, v.x); v.y = fmaf(a.w, xv3.y, v.y);
                v.z = fmaf(a.w, xv3.z, v.z); v.w = fmaf(a.w, xv3.w, v.w);
                acc[r] = v;
            }
        }
        #pragma unroll
        for (int r = 0; r < ROWS; ++r)
            ((float4*)&part[q][r][0])[d4] = acc[r];
    }
    __syncthreads();

    // combine the 8 j-slices: thread handles (r = t>>7 and r+2, d = t&127)
    {
        const int d  = t & 127;
        const int rr = t >> 7;
        #pragma unroll
        for (int rq = 0; rq < 2; ++rq) {
            const int r = rr + rq * 2;
            float s = 0.f;
            #pragma unroll
            for (int q = 0; q < 8; ++q) s += part[q][r][d];
            t_s[r][d] = s;
        }
    }
    __syncthreads();

    // 3) g[r][d] = relu(sum_c t_s[r][c]*W_w[d,c] + W_b[d]) for r in {s, s+2}
    {
        const int s = t >> 7, d = t & 127;
        const int r0 = s, r1 = s + 2;
        float a0 = W_b[d], a1 = a0;
        const float4* wr = (const float4*)(W_w + (size_t)d * Dn);
        const float4* t0 = (const float4*)&t_s[r0][0];
        const float4* t1 = (const float4*)&t_s[r1][0];
        #pragma unroll 8
        for (int c4 = 0; c4 < Dn / 4; ++c4) {
            const float4 w = wr[c4];
            const float4 u0 = t0[c4];
            const float4 u1 = t1[c4];
            a0 = fmaf(u0.x, w.x, a0); a0 = fmaf(u0.y, w.y, a0);
            a0 = fmaf(u0.z, w.z, a0); a0 = fmaf(u0.w, w.w, a0);
            a1 = fmaf(u1.x, w.x, a1); a1 = fmaf(u1.y, w.y, a1);
            a1 = fmaf(u1.z, w.z, a1); a1 = fmaf(u1.w, w.w, a1);
        }
        g_s[r0][d] = fmaxf(a0, 0.f);
        g_s[r1][d] = fmaxf(a1, 0.f);
    }
    __syncthreads();

    // 4) out[b,i0+r,d] = sum_c g_s[r][c]*Wxx_w[d,c] + Wxx_b[d] for r in {s, s+2}
    {
        const int s = t >> 7, d = t & 127;
        const int r0 = s, r1 = s + 2;
        float a0 = Wxx_b[d], a1 = a0;
        const float4* wr = (const float4*)(Wxx_w + (size_t)d * Dn);
        const float4* g0 = (const float4*)&g_s[r0][0];
        const float4* g1 = (const float4*)&g_s[r1][0];
        #pragma unroll 8
        for (int c4 = 0; c4 < Dn / 4; ++c4) {
            const float4 w = wr[c4];
            const float4 u0 = g0[c4];
            const float4 u1 = g1[c4];
            a0 = fmaf(u0.x, w.x, a0); a0 = fmaf(u0.y, w.y, a0);
            a0 = fmaf(u0.z, w.z, a0); a0 = fmaf(u0.w, w.w, a0);
            a1 = fmaf(u1.x, w.x, a1); a1 = fmaf(u1.y, w.y, a1);
            a1 = fmaf(u1.z, w.z, a1); a1 = fmaf(u1.w, w.w, a1);
        }
        out[((size_t)b * Ln + (i0 + r0)) * Dn + d] = a0;
        out[((size_t)b * Ln + (i0 + r1)) * Dn + d] = a1;
    }

    // 5) n1/n2: ROWS*12 = 48 dot-products of length 128
    if (t < ROWS * 2 * Hn) {
        const int r  = t / (2 * Hn);
        const int kk = t % (2 * Hn);
        const int k  = (kk < Hn) ? kk : (kk - Hn);
        const bool isn2 = (kk >= Hn);
        const float* wrow = Wx_w + (size_t)k * WXROW + Hn + (isn2 ? Dn : 0);
        float acc = 0.f;
        #pragma unroll 8
        for (int c = 0; c < Dn; ++c)
            acc = fmaf(g_s[r][c], wrow[c], acc);
        const size_t idx = ((size_t)b * Hn + k) * Ln + (i0 + r);
        if (isn2) n2_ws[idx] = acc;
        else      n1_ws[idx] = acc;
    }
}

// -------- Kernel 2: new_adj — coalesced LDS-staged e, HALF j-tile --------
// grid = B*L*2 blocks (b,i,j-half), 256 threads.
// LDS 16.5 KB -> 8 blocks/CU (32 waves/CU, wave-limited) vs round-0's 4.
// Doubled cross-block stage/compute overlap per CU. Weights/bias/n1 read
// directly from global at wave-uniform addresses -> s_load scalarization,
// no LDS staging or setup branches for them.
#define EPAD 33
__global__ __launch_bounds__(256, 8) void k_adj(
    const float* __restrict__ wadj, const float* __restrict__ e,
    const float* __restrict__ Wx_w, const float* __restrict__ Wx_b,
    const float* __restrict__ n1_ws, const float* __restrict__ n2_ws,
    float* __restrict__ new_adj)
{
    __shared__ float e_lds[128 * EPAD];   // 16.5 KB, padded stride 33

    const int t  = threadIdx.x;
    const int bi = blockIdx.x >> 1;
    const int jh = blockIdx.x & 1;
    const int b  = bi >> 8;
    const int i  = bi & 255;
    const int j0 = jh << 7;               // 0 or 128

    // stage e[b,i,j0:j0+128,:] (16 KB) coalesced into padded LDS
    {
        const float4* ep4 = (const float4*)(e + (((size_t)b * Ln + i) * Ln + j0) * En);
        #pragma unroll
        for (int k = 0; k < 4; ++k) {
            const int idx = t + k * 256;       // float4 index (0..1023)
            const float4 v = ep4[idx];
            const int jl = idx >> 3;           // 8 float4 per j-row
            const int c  = (idx & 7) * 4;
            float* dst = &e_lds[jl * EPAD + c];
            dst[0] = v.x; dst[1] = v.y; dst[2] = v.z; dst[3] = v.w;
        }
    }
    __syncthreads();

    const int jl = t & 127;
    const int kh = t >> 7;                 // 0 or 1 (wave-uniform)
    const int j  = j0 + jl;

    // e row for this j: stride-33 LDS reads, 2-way bank aliasing (free)
    float ev[En];
    {
        const float* src = &e_lds[jl * EPAD];
        #pragma unroll
        for (int c = 0; c < En; ++c) ev[c] = src[c];
    }

    // wadj[b,h,i,j]: 256B-coalesced per wave, L1-shared across kh groups
    float wv[Hn];
    #pragma unroll
    for (int h = 0; h < Hn; ++h)
        wv[h] = wadj[(((size_t)b * Hn + h) * Ln + i) * Ln + j];

    // 3 k's per thread: k = kh + 2q (wave-uniform -> weight rows scalarize)
    #pragma unroll
    for (int q = 0; q < 3; ++q) {
        const int k = kh + 2 * q;
        float acc = Wx_b[k] + n1_ws[((size_t)b * Hn + k) * Ln + i]
                            + n2_ws[((size_t)b * Hn + k) * Ln + j];
        #pragma unroll
        for (int h = 0; h < Hn; ++h)
            acc = fmaf(wv[h], Wx_w[(size_t)k * WXROW + h], acc);
        const float* wr = Wx_w + (size_t)k * WXROW + Hn + 2 * Dn;
        #pragma unroll
        for (int c = 0; c < En; ++c)
            acc = fmaf(ev[c], wr[c], acc);
        new_adj[(((size_t)b * Hn + k) * Ln + i) * Ln + j] = acc;
    }
}

extern "C" void kernel_launch(void* const* d_in, const int* in_sizes, int n_in,
                              void* d_out, int out_size, void* d_ws, size_t ws_size,
                              hipStream_t stream) {
    const float* x      = (const float*)d_in[0];
    const float* wadj   = (const float*)d_in[1];
    const float* e      = (const float*)d_in[2];
    const float* W_w    = (const float*)d_in[3];
    const float* W_b    = (const float*)d_in[4];
    const float* Wx_w   = (const float*)d_in[5];
    const float* Wx_b   = (const float*)d_in[6];
    const float* Wxx_w  = (const float*)d_in[7];
    const float* Wxx_b  = (const float*)d_in[8];

    float* out      = (float*)d_out;                   // (B,L,D)
    float* new_adj  = out + (size_t)Bn * Ln * Dn;      // (B,H,L,L)

    float* n1_ws = (float*)d_ws;                       // (B,H,L)
    float* n2_ws = n1_ws + (size_t)Bn * Hn * Ln;       // (B,H,L)

    k_gcn<<<Bn * (Ln / ROWS), 256, 0, stream>>>(x, wadj, W_w, W_b, Wx_w,
                                                Wxx_w, Wxx_b, out, n1_ws, n2_ws);
    k_adj<<<Bn * Ln * 2, 256, 0, stream>>>(wadj, e, Wx_w, Wx_b, n1_ws, n2_ws, new_adj);
}

// Round 3
// 147.379 us; speedup vs baseline: 1.1852x; 1.1852x over previous
//
#include <hip/hip_runtime.h>

#define Bn 8
#define Ln 256
#define Dn 128
#define Hn 6
#define En 32
#define WXROW (Hn + 2*Dn + En)   // 294
#define ROWS 4                   // i-rows per k_gcn block

// -------- Kernel 1: gcn + out + n1/n2 --------
// grid = B * (L/ROWS) = 512 blocks, 256 threads
__global__ __launch_bounds__(256) void k_gcn(
    const float* __restrict__ x, const float* __restrict__ wadj,
    const float* __restrict__ W_w, const float* __restrict__ W_b,
    const float* __restrict__ Wx_w,
    const float* __restrict__ Wxx_w, const float* __restrict__ Wxx_b,
    float* __restrict__ out, float* __restrict__ n1_ws, float* __restrict__ n2_ws)
{
    __shared__ float adj[ROWS][Ln];        // 4 KB
    __shared__ float part[8][ROWS][Dn];    // 16 KB
    __shared__ float t_s[ROWS][Dn];        // 2 KB
    __shared__ float g_s[ROWS][Dn];        // 2 KB

    const int t  = threadIdx.x;
    const int b  = blockIdx.x >> 6;            // 64 blocks per batch
    const int i0 = (blockIdx.x & 63) * ROWS;

    // 1) adj[r][j] = mean_h wadj[b,h,i0+r,j]  — float4 per thread: (r = t>>6, j4 = t&63)
    {
        const int r  = t >> 6;
        const int j4 = t & 63;
        const float4* w4 = (const float4*)wadj;
        float4 sum = {0.f, 0.f, 0.f, 0.f};
        #pragma unroll
        for (int h = 0; h < Hn; ++h) {
            const float4 v = w4[(((size_t)b * Hn + h) * Ln + (i0 + r)) * (Ln / 4) + j4];
            sum.x += v.x; sum.y += v.y; sum.z += v.z; sum.w += v.w;
        }
        const float inv_h = 1.0f / 6.0f;
        sum.x *= inv_h; sum.y *= inv_h; sum.z *= inv_h; sum.w *= inv_h;
        ((float4*)&adj[0][0])[r * (Ln / 4) + j4] = sum;
    }
    __syncthreads();

    // 2) t[r][d] = sum_j adj[r][j] * x[b,j,d]
    //    256 thr = (q = t>>5 in 0..7: j-slice) x (d4 = t&31: float4 column)
    {
        const int q  = t >> 5;
        const int d4 = t & 31;
        float4 acc[ROWS];
        #pragma unroll
        for (int r = 0; r < ROWS; ++r) acc[r] = {0.f, 0.f, 0.f, 0.f};

        const float4* xp4 = (const float4*)(x + (size_t)b * Ln * Dn) + d4;
        const float4* adj4 = (const float4*)&adj[0][0];
        const int j0 = q * 32;

        #pragma unroll 2
        for (int jj4 = 0; jj4 < 8; ++jj4) {
            const int j = j0 + jj4 * 4;
            const float4 xv0 = xp4[(size_t)(j + 0) * 32];
            const float4 xv1 = xp4[(size_t)(j + 1) * 32];
            const float4 xv2 = xp4[(size_t)(j + 2) * 32];
            const float4 xv3 = xp4[(size_t)(j + 3) * 32];
            #pragma unroll
            for (int r = 0; r < ROWS; ++r) {
                const float4 a = adj4[r * (Ln / 4) + (j >> 2)];
                float4 v = acc[r];
                v.x = fmaf(a.x, xv0.x, v.x); v.y = fmaf(a.x, xv0.y, v.y);
                v.z = fmaf(a.x, xv0.z, v.z); v.w = fmaf(a.x, xv0.w, v.w);
                v.x = fmaf(a.y, xv1.x, v.x); v.y = fmaf(a.y, xv1.y, v.y);
                v.z = fmaf(a.y, xv1.z, v.z); v.w = fmaf(a.y, xv1.w, v.w);
                v.x = fmaf(a.z, xv2.x, v.x); v.y = fmaf(a.z, xv2.y, v.y);
                v.z = fmaf(a.z, xv2.z, v.z); v.w = fmaf(a.z, xv2.w, v.w);
                v.x = fmaf(a.w, xv3.x, v.x); v.y = fmaf(a.w, xv3.y, v.y);
                v.z = fmaf(a.w, xv3.z, v.z); v.w = fmaf(a.w, xv3.w, v.w);
                acc[r] = v;
            }
        }
        #pragma unroll
        for (int r = 0; r < ROWS; ++r)
            ((float4*)&part[q][r][0])[d4] = acc[r];
    }
    __syncthreads();

    // combine the 8 j-slices: thread handles (r = t>>7 and r+2, d = t&127)
    {
        const int d  = t & 127;
        const int rr = t >> 7;
        #pragma unroll
        for (int rq = 0; rq < 2; ++rq) {
            const int r = rr + rq * 2;
            float s = 0.f;
            #pragma unroll
            for (int q = 0; q < 8; ++q) s += part[q][r][d];
            t_s[r][d] = s;
        }
    }
    __syncthreads();

    // 3) g[r][d] = relu(sum_c t_s[r][c]*W_w[d,c] + W_b[d]) for r in {s, s+2}
    {
        const int s = t >> 7, d = t & 127;
        const int r0 = s, r1 = s + 2;
        float a0 = W_b[d], a1 = a0;
        const float4* wr = (const float4*)(W_w + (size_t)d * Dn);
        const float4* t0 = (const float4*)&t_s[r0][0];
        const float4* t1 = (const float4*)&t_s[r1][0];
        #pragma unroll 8
        for (int c4 = 0; c4 < Dn / 4; ++c4) {
            const float4 w = wr[c4];
            const float4 u0 = t0[c4];
            const float4 u1 = t1[c4];
            a0 = fmaf(u0.x, w.x, a0); a0 = fmaf(u0.y, w.y, a0);
            a0 = fmaf(u0.z, w.z, a0); a0 = fmaf(u0.w, w.w, a0);
            a1 = fmaf(u1.x, w.x, a1); a1 = fmaf(u1.y, w.y, a1);
            a1 = fmaf(u1.z, w.z, a1); a1 = fmaf(u1.w, w.w, a1);
        }
        g_s[r0][d] = fmaxf(a0, 0.f);
        g_s[r1][d] = fmaxf(a1, 0.f);
    }
    __syncthreads();

    // 4) out[b,i0+r,d] = sum_c g_s[r][c]*Wxx_w[d,c] + Wxx_b[d] for r in {s, s+2}
    {
        const int s = t >> 7, d = t & 127;
        const int r0 = s, r1 = s + 2;
        float a0 = Wxx_b[d], a1 = a0;
        const float4* wr = (const float4*)(Wxx_w + (size_t)d * Dn);
        const float4* g0 = (const float4*)&g_s[r0][0];
        const float4* g1 = (const float4*)&g_s[r1][0];
        #pragma unroll 8
        for (int c4 = 0; c4 < Dn / 4; ++c4) {
            const float4 w = wr[c4];
            const float4 u0 = g0[c4];
            const float4 u1 = g1[c4];
            a0 = fmaf(u0.x, w.x, a0); a0 = fmaf(u0.y, w.y, a0);
            a0 = fmaf(u0.z, w.z, a0); a0 = fmaf(u0.w, w.w, a0);
            a1 = fmaf(u1.x, w.x, a1); a1 = fmaf(u1.y, w.y, a1);
            a1 = fmaf(u1.z, w.z, a1); a1 = fmaf(u1.w, w.w, a1);
        }
        out[((size_t)b * Ln + (i0 + r0)) * Dn + d] = a0;
        out[((size_t)b * Ln + (i0 + r1)) * Dn + d] = a1;
    }

    // 5) n1/n2: ROWS*12 = 48 dot-products of length 128
    if (t < ROWS * 2 * Hn) {
        const int r  = t / (2 * Hn);
        const int kk = t % (2 * Hn);
        const int k  = (kk < Hn) ? kk : (kk - Hn);
        const bool isn2 = (kk >= Hn);
        const float* wrow = Wx_w + (size_t)k * WXROW + Hn + (isn2 ? Dn : 0);
        float acc = 0.f;
        #pragma unroll 8
        for (int c = 0; c < Dn; ++c)
            acc = fmaf(g_s[r][c], wrow[c], acc);
        const size_t idx = ((size_t)b * Hn + k) * Ln + (i0 + r);
        if (isn2) n2_ws[idx] = acc;
        else      n1_ws[idx] = acc;
    }
}

// -------- Kernel 2: new_adj — round-0 structure, 512 threads (k-split) -----
// grid = B*L blocks (b,i), 512 threads. Full 256-j e tile staged (32 KB) into
// padded LDS exactly as round 0. Change vs round 0: 8 waves/block with the
// 6 k's split across two kh-halves (3 per thread) -> LDS-limited 4 blocks/CU
// now carries 32 waves/CU (was 16), doubling stage/compute overlap across
// blocks. NO min-wave launch bound: round 2 proved (,8) drives the allocator
// to 32 VGPRs + ~10 dwords/thread scratch spill (WRITE_SIZE 52 MiB vs 13).
#define EPAD 33
__global__ __launch_bounds__(512) void k_adj(
    const float* __restrict__ wadj, const float* __restrict__ e,
    const float* __restrict__ Wx_w, const float* __restrict__ Wx_b,
    const float* __restrict__ n1_ws, const float* __restrict__ n2_ws,
    float* __restrict__ new_adj)
{
    __shared__ float e_lds[Ln * EPAD];   // 33 KB, padded stride 33
    __shared__ float Wa_s[Hn][Hn];
    __shared__ float We_s[Hn][En];
    __shared__ float bias_n1[Hn];        // Wx_b[k] + n1[b,k,i]

    const int t = threadIdx.x;
    const int b = blockIdx.x >> 8;
    const int i = blockIdx.x & 255;

    if (t < Hn * Hn) {
        const int k = t / Hn, h = t % Hn;
        Wa_s[k][h] = Wx_w[(size_t)k * WXROW + h];
    }
    if (t >= 64 && t < 64 + Hn * En) {
        const int q = t - 64, k = q / En, c = q % En;
        We_s[k][c] = Wx_w[(size_t)k * WXROW + Hn + 2 * Dn + c];
    }
    if (t >= 32 && t < 32 + Hn) {
        const int k = t - 32;
        bias_n1[k] = Wx_b[k] + n1_ws[((size_t)b * Hn + k) * Ln + i];
    }

    // stage e[b,i,:,:] (256x32 floats = 32 KB) coalesced into padded LDS
    // 512 threads x 4 float4 = 2048 float4
    {
        const float4* ep4 = (const float4*)(e + (((size_t)b * Ln + i) * Ln) * En);
        #pragma unroll
        for (int k = 0; k < 4; ++k) {
            const int idx = t + k * 512;       // float4 index (0..2047)
            const float4 v = ep4[idx];
            const int j = idx >> 3;            // 8 float4 per j-row
            const int c = (idx & 7) * 4;
            float* dst = &e_lds[j * EPAD + c];
            dst[0] = v.x; dst[1] = v.y; dst[2] = v.z; dst[3] = v.w;
        }
    }
    __syncthreads();

    const int j  = t & 255;
    const int kh = t >> 8;                 // 0 or 1, wave-uniform

    float ev[En];
    {
        const float* src = &e_lds[j * EPAD];
        #pragma unroll
        for (int c = 0; c < En; ++c) ev[c] = src[c];
    }

    float wv[Hn];
    #pragma unroll
    for (int h = 0; h < Hn; ++h)
        wv[h] = wadj[(((size_t)b * Hn + h) * Ln + i) * Ln + j];

    // 3 k's per thread: k = kh*3 + q (wave-uniform)
    #pragma unroll
    for (int q = 0; q < 3; ++q) {
        const int k = kh * 3 + q;
        float acc = bias_n1[k] + n2_ws[((size_t)b * Hn + k) * Ln + j];
        #pragma unroll
        for (int h = 0; h < Hn; ++h)
            acc = fmaf(wv[h], Wa_s[k][h], acc);
        #pragma unroll
        for (int c = 0; c < En; ++c)
            acc = fmaf(ev[c], We_s[k][c], acc);
        new_adj[(((size_t)b * Hn + k) * Ln + i) * Ln + j] = acc;
    }
}

extern "C" void kernel_launch(void* const* d_in, const int* in_sizes, int n_in,
                              void* d_out, int out_size, void* d_ws, size_t ws_size,
                              hipStream_t stream) {
    const float* x      = (const float*)d_in[0];
    const float* wadj   = (const float*)d_in[1];
    const float* e      = (const float*)d_in[2];
    const float* W_w    = (const float*)d_in[3];
    const float* W_b    = (const float*)d_in[4];
    const float* Wx_w   = (const float*)d_in[5];
    const float* Wx_b   = (const float*)d_in[6];
    const float* Wxx_w  = (const float*)d_in[7];
    const float* Wxx_b  = (const float*)d_in[8];

    float* out      = (float*)d_out;                   // (B,L,D)
    float* new_adj  = out + (size_t)Bn * Ln * Dn;      // (B,H,L,L)

    float* n1_ws = (float*)d_ws;                       // (B,H,L)
    float* n2_ws = n1_ws + (size_t)Bn * Hn * Ln;       // (B,H,L)

    k_gcn<<<Bn * (Ln / ROWS), 256, 0, stream>>>(x, wadj, W_w, W_b, Wx_w,
                                                Wxx_w, Wxx_b, out, n1_ws, n2_ws);
    k_adj<<<Bn * Ln, 512, 0, stream>>>(wadj, e, Wx_w, Wx_b, n1_ws, n2_ws, new_adj);
}